// Round 1
// 1165.069 us; speedup vs baseline: 1.0103x; 1.0103x over previous
//
#include <hip/hip_runtime.h>

typedef unsigned short u16;
typedef __attribute__((ext_vector_type(4))) float f4;
typedef __attribute__((ext_vector_type(8))) __bf16 bf16x8;
typedef __attribute__((ext_vector_type(4))) float f32x4;

#define D_MODEL 2048
#define D_SSM 4096
#define D_STATE 128
#define NHEADS 64
#define HEADDIM 64
#define CHUNK 64
#define LTOT 4096
#define NB 2
#define CONV_DIM 4352
#define XBC_LD 4480   // 4352 conv channels + 64 dt + 64 pad

__device__ inline float bf2f(unsigned v) { return __uint_as_float(v << 16); }
__device__ inline u16 f2bf(float f) {
    unsigned u = __float_as_uint(f);
    unsigned r = (u + 0x7fffu + ((u >> 16) & 1u)) >> 16;
    return (u16)r;
}
__device__ inline unsigned pack2(float a, float b) {
    return (unsigned)f2bf(a) | ((unsigned)f2bf(b) << 16);
}
__device__ inline void gload_lds16(const void* g, void* l) {
    __builtin_amdgcn_global_load_lds((const __attribute__((address_space(1))) void*)g,
                                     (__attribute__((address_space(3))) void*)l, 16, 0, 0);
}

// ---------------- f32 -> bf16 cast ----------------
__global__ __launch_bounds__(256) void tobf16_kernel(const float* __restrict__ src,
                                                     u16* __restrict__ dst, int n4) {
    int i = blockIdx.x * 256 + threadIdx.x;
    if (i < n4) {
        f4 v = ((const f4*)src)[i];
        uint2 pk;
        pk.x = pack2(v[0], v[1]);
        pk.y = pack2(v[2], v[3]);
        ((uint2*)dst)[i] = pk;
    }
}

// W_in (8512 x 2048) f32 -> win_bf (8576 x 2048) bf16, pad rows zero
__global__ __launch_bounds__(256) void winpad_kernel(const float* __restrict__ src,
                                                     u16* __restrict__ dst) {
    int i = blockIdx.x * 256 + threadIdx.x;
    if (i >= (8576 * 2048 / 4)) return;
    int col4 = i & 511;
    int row = i >> 9;
    f4 v = {0.f, 0.f, 0.f, 0.f};
    if (row < 8512) v = ((const f4*)src)[row * 512 + col4];
    uint2 pk;
    pk.x = pack2(v[0], v[1]);
    pk.y = pack2(v[2], v[3]);
    ((uint2*)dst)[i] = pk;
}

// ---------------- GEMM: C[m,n] = sum_k A[m,k]*B[n,k]; bf16 in; f32 or bf16 out ----
template <int OUT_BF16>
__global__ __launch_bounds__(256) void gemm_bt(const u16* __restrict__ A,
                                               const u16* __restrict__ B,
                                               void* __restrict__ Cp, int K, int ldC) {
    __shared__ u16 As[128 * 32];
    __shared__ u16 Bsm[128 * 32];
    int t = threadIdx.x, w = t >> 6, lane = t & 63;
    int blockM = blockIdx.y * 128, blockN = blockIdx.x * 128;
    int wm = (w & 1) * 64, wn = (w >> 1) * 64;

    const u16* Ab = A + (size_t)(blockM + 32 * w + (lane >> 2)) * K + (lane & 3) * 8;
    const u16* Bb = B + (size_t)(blockN + 32 * w + (lane >> 2)) * K + (lane & 3) * 8;
    u16* AsW = As + w * 1024;
    u16* BsW = Bsm + w * 1024;

    f32x4 acc[4][4] = {};
    const bf16x8* As8 = (const bf16x8*)As;
    const bf16x8* Bs8 = (const bf16x8*)Bsm;
    int aoff = (wm + (lane & 15)) * 4 + (lane >> 4);
    int boff = (wn + (lane & 15)) * 4 + (lane >> 4);

    for (int k0 = 0; k0 < K; k0 += 32) {
        const u16* Ag = Ab + k0;
        const u16* Bg = Bb + k0;
        gload_lds16(Ag, AsW);
        gload_lds16(Ag + (size_t)16 * K, AsW + 512);
        gload_lds16(Bg, BsW);
        gload_lds16(Bg + (size_t)16 * K, BsW + 512);
        __syncthreads();
        bf16x8 af[4], bfv[4];
#pragma unroll
        for (int i = 0; i < 4; i++) af[i] = As8[aoff + 64 * i];
#pragma unroll
        for (int j = 0; j < 4; j++) bfv[j] = Bs8[boff + 64 * j];
#pragma unroll
        for (int i = 0; i < 4; i++)
#pragma unroll
            for (int j = 0; j < 4; j++)
                acc[i][j] = __builtin_amdgcn_mfma_f32_16x16x32_bf16(af[i], bfv[j], acc[i][j], 0, 0, 0);
        __syncthreads();
    }
    int rbase = blockM + wm + (lane >> 4) * 4;
    int cbase = blockN + wn + (lane & 15);
    if (OUT_BF16) {
        u16* C = (u16*)Cp;
#pragma unroll
        for (int i = 0; i < 4; i++)
#pragma unroll
            for (int j = 0; j < 4; j++)
#pragma unroll
                for (int r = 0; r < 4; r++)
                    C[(size_t)(rbase + 16 * i + r) * ldC + cbase + 16 * j] = f2bf(acc[i][j][r]);
    } else {
        float* C = (float*)Cp;
#pragma unroll
        for (int i = 0; i < 4; i++)
#pragma unroll
            for (int j = 0; j < 4; j++)
#pragma unroll
                for (int r = 0; r < 4; r++)
                    C[(size_t)(rbase + 16 * i + r) * ldC + cbase + 16 * j] = acc[i][j][r];
    }
}

// ---------------- depthwise causal conv(4) + bias + silu; bf16 in/out ----------------
__global__ __launch_bounds__(256) void conv_kernel(const u16* __restrict__ xbcdt,
                                                   const float* __restrict__ conv_w,
                                                   const float* __restrict__ conv_b,
                                                   u16* __restrict__ convO) {
    int ch = blockIdx.x * 256 + threadIdx.x;  // 17*256 = 4352 exact
    int row = blockIdx.y;                     // 8192
    int l = row & (LTOT - 1);
    f4 w = *(const f4*)&conv_w[ch * 4];
    float acc = conv_b[ch];
#pragma unroll
    for (int k = 0; k < 4; ++k) {
        int ls = l - 3 + k;
        if (ls >= 0) acc += bf2f(xbcdt[(size_t)(row - 3 + k) * XBC_LD + ch]) * w[k];
    }
    convO[(size_t)row * CONV_DIM + ch] = f2bf(acc / (1.f + __expf(-acc)));
}

// ---------------- dt = softplus(raw + bias) -> dtp[row][h] f32 ----------------
__global__ __launch_bounds__(256) void dt_kernel(const u16* __restrict__ xbcdt,
                                                 const float* __restrict__ dt_bias,
                                                 float* __restrict__ dtp) {
    int idx = blockIdx.x * 256 + threadIdx.x;
    if (idx >= NB * LTOT * NHEADS) return;
    int row = idx >> 6, h = idx & 63;
    float x = bf2f(xbcdt[(size_t)row * XBC_LD + CONV_DIM + h]) + dt_bias[h];
    dtp[idx] = (x > 15.f) ? x : log1pf(__expf(x));
}

// ---------------- CB[l,s] = sum_n C[l,n]*B[s,n] per (b,c) -> CBb f32 ----------------
__global__ __launch_bounds__(256) void cb_kernel(const u16* __restrict__ convO,
                                                 float* __restrict__ CBb) {
    __shared__ u16 Bt[128 * 68];  // [n][s]
    __shared__ u16 Ct[128 * 68];  // [n][l]
    int bc = blockIdx.x;
    int c = bc & 63, b = bc >> 6;
    int rowbase = b * LTOT + c * CHUNK;
    int t = threadIdx.x;
#pragma unroll
    for (int i = 0; i < 32; i++) {
        int idx = i * 256 + t;
        int s = idx >> 7, n = idx & 127;
        Bt[n * 68 + s] = convO[(size_t)(rowbase + s) * CONV_DIM + D_SSM + n];
        Ct[n * 68 + s] = convO[(size_t)(rowbase + s) * CONV_DIM + D_SSM + D_STATE + n];
    }
    __syncthreads();
    int sq = t & 15, lq = t >> 4;
    f4 acc[4] = {};
#pragma unroll 4
    for (int n = 0; n < 128; n++) {
        ushort4 bv = *(const ushort4*)&Bt[n * 68 + sq * 4];
        ushort4 cv = *(const ushort4*)&Ct[n * 68 + lq * 4];
        f4 bf;
        bf[0] = bf2f(bv.x); bf[1] = bf2f(bv.y); bf[2] = bf2f(bv.z); bf[3] = bf2f(bv.w);
        float c0 = bf2f(cv.x), c1 = bf2f(cv.y), c2 = bf2f(cv.z), c3 = bf2f(cv.w);
        acc[0] += c0 * bf; acc[1] += c1 * bf; acc[2] += c2 * bf; acc[3] += c3 * bf;
    }
    float* outb = CBb + (size_t)bc * 4096;
#pragma unroll
    for (int j = 0; j < 4; j++) *(f4*)&outb[(lq * 4 + j) * 64 + sq * 4] = acc[j];
}

// ---------------- fused SSM, MFMA version (double-buffered, 1 barrier/chunk) ----------
// grid 512 = (b 2) x (h 64) x (pg 4); block 256 (4 waves); sequential over 64 chunks.
// Iteration: issue next-chunk global loads -> compute chunk c from buf[cur] ->
// write regs into buf[nxt] (incl. dt-scan + post-update state Sd) -> ONE barrier.
// Reads hit buf[cur], writes hit buf[nxt], so a single barrier per chunk is safe:
// between two barriers all waves are in the same iteration.
__global__ __launch_bounds__(256, 2) void ssm_mfma(const u16* __restrict__ convO,
                                                   const float* __restrict__ dtp,
                                                   const float* __restrict__ CBb,
                                                   const float* __restrict__ A_log,
                                                   const float* __restrict__ Dvec,
                                                   u16* __restrict__ ybf) {
    __shared__ __align__(16) u16 xT[2][16 * 72];    // [p'][l]
    __shared__ __align__(16) u16 BT[2][128 * 72];   // [n][l]
    __shared__ __align__(16) u16 Sd[2][16 * 136];   // [p'][n]
    __shared__ __align__(16) float scal[2][256];    // dts|acs|wls|els, 64 each

    int t = threadIdx.x;
    int w = t >> 6, lane = t & 63;
    int z = blockIdx.x;
    int pg = z & 3, h = (z >> 2) & 63, b = z >> 8;
    int pbase = h * 64 + pg * 16;
    float Ah = -__expf(A_log[h]);
    float Dh = Dvec[h];

    int fm = lane & 15;        // within-tile row/col index
    int fq = lane >> 4;        // quad 0..3
    int fk = fq * 8;           // k-base within a 32-wide k-step
    int sl = t & 63;           // staging: row l
    int sq = t >> 6;           // staging: quarter

    f32x4 sacc[2] = {};        // state acc: element (p' = fq*4+r, n = 32w+16nt+fm)

    const float* CBbase = CBb + (size_t)(b * 64) * 4096;

    // ---------- prologue: stage chunk 0 into buffers[0] ----------
    {
        int rowbase = b * LTOT;
        const u16* rowp = convO + (size_t)rowbase * CONV_DIM;
        if (t < 64) {
            float dtv = dtp[(size_t)(rowbase + t) * 64 + h];
            float v = dtv * Ah;
#pragma unroll
            for (int off = 1; off < 64; off <<= 1) {
                float pv = __shfl_up(v, off, 64);
                if (t >= off) v += pv;
            }
            float alast = __shfl(v, 63, 64);
            scal[0][t] = dtv;
            scal[0][64 + t] = v;
            scal[0][128 + t] = dtv * __expf(alast - v);
            scal[0][192 + t] = __expf(v);
        }
        ushort4 xv = *(const ushort4*)(rowp + (size_t)sl * CONV_DIM + pbase + sq * 4);
        xT[0][(sq * 4 + 0) * 72 + sl] = xv.x;
        xT[0][(sq * 4 + 1) * 72 + sl] = xv.y;
        xT[0][(sq * 4 + 2) * 72 + sl] = xv.z;
        xT[0][(sq * 4 + 3) * 72 + sl] = xv.w;
        {
            const uint4* bp = (const uint4*)(rowp + (size_t)sl * CONV_DIM + D_SSM + sq * 32);
            uint4 bvp[4];
#pragma unroll
            for (int q = 0; q < 4; ++q) bvp[q] = bp[q];
            const u16* bs = (const u16*)bvp;
#pragma unroll
            for (int i = 0; i < 32; ++i) BT[0][(sq * 32 + i) * 72 + sl] = bs[i];
        }
#pragma unroll
        for (int nt = 0; nt < 2; ++nt)
#pragma unroll
            for (int r = 0; r < 4; ++r)
                Sd[0][(fq * 4 + r) * 136 + 32 * w + 16 * nt + fm] = 0;
        __syncthreads();
    }

    int cur = 0;
    for (int c = 0; c < 64; ++c, cur ^= 1) {
        int rowbase = b * LTOT + c * CHUNK;
        const u16* rowp = convO + (size_t)rowbase * CONV_DIM;
        int yl = 16 * w + fm;  // A-operand row l for Y mfmas

        // ---- current-chunk operand prefetch (global -> regs) ----
        const u16* Cg = rowp + (size_t)yl * CONV_DIM + D_SSM + D_STATE;
        bf16x8 afr[4];
#pragma unroll
        for (int kk = 0; kk < 4; ++kk) afr[kk] = *(const bf16x8*)(Cg + kk * 32 + fk);
        const float* CBrow = CBbase + (size_t)c * 4096 + yl * 64;
        f4 cbr[2][2];
#pragma unroll
        for (int kk = 0; kk < 2; ++kk) {
            cbr[kk][0] = *(const f4*)&CBrow[kk * 32 + fk];
            cbr[kk][1] = *(const f4*)&CBrow[kk * 32 + fk + 4];
        }

        // ---- next-chunk staging loads (global -> regs, consumed in write phase) ----
        uint4 bv[4] = {};
        ushort4 xv = {0, 0, 0, 0};
        float dtv = 0.f;
        if (c < 63) {
            const u16* rowp1 = rowp + (size_t)CHUNK * CONV_DIM;
            const uint4* bp = (const uint4*)(rowp1 + (size_t)sl * CONV_DIM + D_SSM + sq * 32);
#pragma unroll
            for (int q = 0; q < 4; ++q) bv[q] = bp[q];
            xv = *(const ushort4*)(rowp1 + (size_t)sl * CONV_DIM + pbase + sq * 4);
            if (t < 64) dtv = dtp[(size_t)(rowbase + CHUNK + t) * 64 + h];
        }

        const float* sc = scal[cur];
        const u16* xTc = xT[cur];
        const u16* BTc = BT[cur];
        const u16* Sdc = Sd[cur];

        // ---- Y_off = C . S^T ----
        f32x4 yacc = {0.f, 0.f, 0.f, 0.f};
#pragma unroll
        for (int kk = 0; kk < 4; ++kk) {
            bf16x8 bfr = *(const bf16x8*)&Sdc[fm * 136 + kk * 32 + fk];
            yacc = __builtin_amdgcn_mfma_f32_16x16x32_bf16(afr[kk], bfr, yacc, 0, 0, 0);
        }
#pragma unroll
        for (int r = 0; r < 4; ++r) yacc[r] *= sc[192 + 16 * w + fq * 4 + r];

        // ---- Y_diag = G . x ----
        {
            float acl = sc[64 + yl];
#pragma unroll
            for (int kk = 0; kk < 2; ++kk) {
                int s0 = kk * 32 + fk;
                f4 cb0 = cbr[kk][0];
                f4 cb1 = cbr[kk][1];
                f4 ac0 = *(const f4*)&sc[64 + s0];
                f4 ac1 = *(const f4*)&sc[64 + s0 + 4];
                f4 dt0 = *(const f4*)&sc[s0];
                f4 dt1 = *(const f4*)&sc[s0 + 4];
                union { u16 us[8]; bf16x8 v; } gu;
#pragma unroll
                for (int j = 0; j < 4; ++j) {
                    int s = s0 + j;
                    float gv = (s <= yl) ? cb0[j] * __expf(acl - ac0[j]) * dt0[j] : 0.f;
                    gu.us[j] = f2bf(gv);
                }
#pragma unroll
                for (int j = 0; j < 4; ++j) {
                    int s = s0 + 4 + j;
                    float gv = (s <= yl) ? cb1[j] * __expf(acl - ac1[j]) * dt1[j] : 0.f;
                    gu.us[4 + j] = f2bf(gv);
                }
                bf16x8 xfr = *(const bf16x8*)&xTc[fm * 72 + s0];
                yacc = __builtin_amdgcn_mfma_f32_16x16x32_bf16(gu.v, xfr, yacc, 0, 0, 0);
            }
        }

        // ---- epilogue: += D*x, write y (bf16) ----
#pragma unroll
        for (int r = 0; r < 4; ++r) {
            int l = 16 * w + fq * 4 + r;
            float xvv = bf2f(xTc[fm * 72 + l]);
            float yv = yacc[r] + Dh * xvv;
            ybf[(size_t)(rowbase + l) * D_SSM + pbase + fm] = f2bf(yv);
        }

        // ---- state update: S = cd*S + (w.x)^T . B ----
        float cd = sc[192 + 63];
        sacc[0] *= cd;
        sacc[1] *= cd;
#pragma unroll
        for (int kk = 0; kk < 2; ++kk) {
            int l0 = kk * 32 + fk;
            ushort4 x0 = *(const ushort4*)&xTc[fm * 72 + l0];
            ushort4 x1 = *(const ushort4*)&xTc[fm * 72 + l0 + 4];
            f4 w0 = *(const f4*)&sc[128 + l0];
            f4 w1 = *(const f4*)&sc[128 + l0 + 4];
            union { u16 us[8]; bf16x8 v; } au;
            au.us[0] = f2bf(bf2f(x0.x) * w0[0]);
            au.us[1] = f2bf(bf2f(x0.y) * w0[1]);
            au.us[2] = f2bf(bf2f(x0.z) * w0[2]);
            au.us[3] = f2bf(bf2f(x0.w) * w0[3]);
            au.us[4] = f2bf(bf2f(x1.x) * w1[0]);
            au.us[5] = f2bf(bf2f(x1.y) * w1[1]);
            au.us[6] = f2bf(bf2f(x1.z) * w1[2]);
            au.us[7] = f2bf(bf2f(x1.w) * w1[3]);
#pragma unroll
            for (int nt = 0; nt < 2; ++nt) {
                bf16x8 bfr = *(const bf16x8*)&BTc[(32 * w + 16 * nt + fm) * 72 + l0];
                sacc[nt] = __builtin_amdgcn_mfma_f32_16x16x32_bf16(au.v, bfr, sacc[nt], 0, 0, 0);
            }
        }

        // ---- write phase: stage chunk c+1 into buffers[nxt] ----
        if (c < 63) {
            int nxt = cur ^ 1;
            if (t < 64) {
                float v = dtv * Ah;
#pragma unroll
                for (int off = 1; off < 64; off <<= 1) {
                    float pv = __shfl_up(v, off, 64);
                    if (t >= off) v += pv;
                }
                float alast = __shfl(v, 63, 64);
                scal[nxt][t] = dtv;
                scal[nxt][64 + t] = v;
                scal[nxt][128 + t] = dtv * __expf(alast - v);
                scal[nxt][192 + t] = __expf(v);
            }
            xT[nxt][(sq * 4 + 0) * 72 + sl] = xv.x;
            xT[nxt][(sq * 4 + 1) * 72 + sl] = xv.y;
            xT[nxt][(sq * 4 + 2) * 72 + sl] = xv.z;
            xT[nxt][(sq * 4 + 3) * 72 + sl] = xv.w;
            {
                const u16* bs = (const u16*)bv;
#pragma unroll
                for (int i = 0; i < 32; ++i) BT[nxt][(sq * 32 + i) * 72 + sl] = bs[i];
            }
#pragma unroll
            for (int nt = 0; nt < 2; ++nt)
#pragma unroll
                for (int r = 0; r < 4; ++r)
                    Sd[nxt][(fq * 4 + r) * 136 + 32 * w + 16 * nt + fm] = f2bf(sacc[nt][r]);
        }
        __syncthreads();
    }
}

// ---------------- gate (silu(z)) + RMSNorm, in-place on y_bf ----------------
__global__ __launch_bounds__(256) void gate_norm(const u16* __restrict__ zbf,
                                                 const float* __restrict__ normw,
                                                 u16* __restrict__ ybf) {
    int row = blockIdx.x, t = threadIdx.x;
    const uint2* y2 = (const uint2*)(ybf + (size_t)row * D_SSM);
    const uint2* z2 = (const uint2*)(zbf + (size_t)row * D_SSM);
    f4 yg[4];
    float ss = 0.f;
#pragma unroll
    for (int i = 0; i < 4; ++i) {
        int idx = i * 256 + t;
        uint2 yv = y2[idx], zv = z2[idx];
        float ya[4] = {bf2f(yv.x & 0xffffu), bf2f(yv.x >> 16), bf2f(yv.y & 0xffffu), bf2f(yv.y >> 16)};
        float za[4] = {bf2f(zv.x & 0xffffu), bf2f(zv.x >> 16), bf2f(zv.y & 0xffffu), bf2f(zv.y >> 16)};
        f4 g;
#pragma unroll
        for (int k = 0; k < 4; ++k) {
            float sz = za[k] / (1.f + __expf(-za[k]));
            g[k] = ya[k] * sz;
            ss += g[k] * g[k];
        }
        yg[i] = g;
    }
#pragma unroll
    for (int off = 32; off; off >>= 1) ss += __shfl_down(ss, off, 64);
    __shared__ float red[4];
    if ((t & 63) == 0) red[t >> 6] = ss;
    __syncthreads();
    float tot = red[0] + red[1] + red[2] + red[3];
    float scale = rsqrtf(tot / (float)D_SSM + 1e-5f);
    const f4* nw4 = (const f4*)normw;
    uint2* out = (uint2*)(ybf + (size_t)row * D_SSM);
#pragma unroll
    for (int i = 0; i < 4; ++i) {
        int idx = i * 256 + t;
        f4 v = yg[i] * scale * nw4[idx];
        uint2 pk;
        pk.x = pack2(v[0], v[1]);
        pk.y = pack2(v[2], v[3]);
        out[idx] = pk;
    }
}

// ---------------- launch ----------------
extern "C" void kernel_launch(void* const* d_in, const int* in_sizes, int n_in,
                              void* d_out, int out_size, void* d_ws, size_t ws_size,
                              hipStream_t stream) {
    const float* u = (const float*)d_in[0];
    const float* W_in = (const float*)d_in[1];
    const float* conv_w = (const float*)d_in[2];
    const float* conv_b = (const float*)d_in[3];
    const float* dt_bias = (const float*)d_in[4];
    const float* A_log = (const float*)d_in[5];
    const float* Dv = (const float*)d_in[6];
    const float* normw = (const float*)d_in[7];
    const float* W_out = (const float*)d_in[8];
    float* out = (float*)d_out;
    char* ws = (char*)d_ws;

    // workspace layout (total 216,006,656 B ~= 206 MiB) — same proven layout as round 2
    u16* z_bf = (u16*)(ws + 0ULL);              //  8192x4096 bf16 = 67,108,864
    u16* xbcdt = (u16*)(ws + 67108864ULL);      //  8192x4480 bf16 = 73,400,320
    u16* y_bf = xbcdt;                          //  overlay: 8192x4096 bf16 (xbcdt dead after conv+dt)
    u16* convO = (u16*)(ws + 140509184ULL);     //  8192x4352 bf16 = 71,303,168
    u16* u_bf = convO;                          //  overlay: 33,554,432 (dead before conv writes)
    u16* win_bf = (u16*)(ws + 174063616ULL);    //  overlay: 35,127,296 (dead before conv writes)
    u16* wout_bf = convO;                       //  overlay: 16,777,216 (after ssm)
    float* dtp = (float*)(ws + 211812352ULL);   //  8192x64 f32 = 2,097,152
    float* CBb = (float*)(ws + 213909504ULL);   //  128x64x64 f32 = 2,097,152

    tobf16_kernel<<<16384, 256, 0, stream>>>(u, u_bf, 4194304);
    winpad_kernel<<<17152, 256, 0, stream>>>(W_in, win_bf);
    gemm_bt<1><<<dim3(32, 64), 256, 0, stream>>>(u_bf, win_bf, z_bf, 2048, 4096);
    gemm_bt<1><<<dim3(35, 64), 256, 0, stream>>>(u_bf, win_bf + (size_t)4096 * 2048, xbcdt, 2048, XBC_LD);
    conv_kernel<<<dim3(17, 8192), 256, 0, stream>>>(xbcdt, conv_w, conv_b, convO);
    dt_kernel<<<2048, 256, 0, stream>>>(xbcdt, dt_bias, dtp);
    cb_kernel<<<128, 256, 0, stream>>>(convO, CBb);
    ssm_mfma<<<512, 256, 0, stream>>>(convO, dtp, CBb, A_log, Dv, y_bf);
    tobf16_kernel<<<8192, 256, 0, stream>>>(W_out, wout_bf, 2097152);
    gate_norm<<<8192, 256, 0, stream>>>(z_bf, normw, y_bf);
    gemm_bt<0><<<dim3(16, 64), 256, 0, stream>>>(y_bf, wout_bf, out, 4096, 2048);
}

// Round 2
// 1132.941 us; speedup vs baseline: 1.0389x; 1.0284x over previous
//
#include <hip/hip_runtime.h>

typedef unsigned short u16;
typedef __attribute__((ext_vector_type(4))) float f4;
typedef __attribute__((ext_vector_type(8))) __bf16 bf16x8;
typedef __attribute__((ext_vector_type(4))) float f32x4;

#define D_MODEL 2048
#define D_SSM 4096
#define D_STATE 128
#define NHEADS 64
#define HEADDIM 64
#define CHUNK 64
#define LTOT 4096
#define NB 2
#define CONV_DIM 4352
#define XBC_LD 4480   // 4352 conv channels + 64 dt + 64 pad

__device__ inline float bf2f(unsigned v) { return __uint_as_float(v << 16); }
__device__ inline u16 f2bf(float f) {
    unsigned u = __float_as_uint(f);
    unsigned r = (u + 0x7fffu + ((u >> 16) & 1u)) >> 16;
    return (u16)r;
}
__device__ inline unsigned pack2(float a, float b) {
    return (unsigned)f2bf(a) | ((unsigned)f2bf(b) << 16);
}
__device__ inline void gload_lds16(const void* g, void* l) {
    __builtin_amdgcn_global_load_lds((const __attribute__((address_space(1))) void*)g,
                                     (__attribute__((address_space(3))) void*)l, 16, 0, 0);
}

// ---------------- f32 -> bf16 cast ----------------
__global__ __launch_bounds__(256) void tobf16_kernel(const float* __restrict__ src,
                                                     u16* __restrict__ dst, int n4) {
    int i = blockIdx.x * 256 + threadIdx.x;
    if (i < n4) {
        f4 v = ((const f4*)src)[i];
        uint2 pk;
        pk.x = pack2(v[0], v[1]);
        pk.y = pack2(v[2], v[3]);
        ((uint2*)dst)[i] = pk;
    }
}

// W_in (8512 x 2048) f32 -> win_bf (8576 x 2048) bf16, pad rows zero
__global__ __launch_bounds__(256) void winpad_kernel(const float* __restrict__ src,
                                                     u16* __restrict__ dst) {
    int i = blockIdx.x * 256 + threadIdx.x;
    if (i >= (8576 * 2048 / 4)) return;
    int col4 = i & 511;
    int row = i >> 9;
    f4 v = {0.f, 0.f, 0.f, 0.f};
    if (row < 8512) v = ((const f4*)src)[row * 512 + col4];
    uint2 pk;
    pk.x = pack2(v[0], v[1]);
    pk.y = pack2(v[2], v[3]);
    ((uint2*)dst)[i] = pk;
}

// ---------------- GEMM: C[m,n] = sum_k A[m,k]*B[n,k]; bf16 in; f32 or bf16 out ----
template <int OUT_BF16>
__global__ __launch_bounds__(256) void gemm_bt(const u16* __restrict__ A,
                                               const u16* __restrict__ B,
                                               void* __restrict__ Cp, int K, int ldC) {
    __shared__ u16 As[128 * 32];
    __shared__ u16 Bsm[128 * 32];
    int t = threadIdx.x, w = t >> 6, lane = t & 63;
    int blockM = blockIdx.y * 128, blockN = blockIdx.x * 128;
    int wm = (w & 1) * 64, wn = (w >> 1) * 64;

    const u16* Ab = A + (size_t)(blockM + 32 * w + (lane >> 2)) * K + (lane & 3) * 8;
    const u16* Bb = B + (size_t)(blockN + 32 * w + (lane >> 2)) * K + (lane & 3) * 8;
    u16* AsW = As + w * 1024;
    u16* BsW = Bsm + w * 1024;

    f32x4 acc[4][4] = {};
    const bf16x8* As8 = (const bf16x8*)As;
    const bf16x8* Bs8 = (const bf16x8*)Bsm;
    int aoff = (wm + (lane & 15)) * 4 + (lane >> 4);
    int boff = (wn + (lane & 15)) * 4 + (lane >> 4);

    for (int k0 = 0; k0 < K; k0 += 32) {
        const u16* Ag = Ab + k0;
        const u16* Bg = Bb + k0;
        gload_lds16(Ag, AsW);
        gload_lds16(Ag + (size_t)16 * K, AsW + 512);
        gload_lds16(Bg, BsW);
        gload_lds16(Bg + (size_t)16 * K, BsW + 512);
        __syncthreads();
        bf16x8 af[4], bfv[4];
#pragma unroll
        for (int i = 0; i < 4; i++) af[i] = As8[aoff + 64 * i];
#pragma unroll
        for (int j = 0; j < 4; j++) bfv[j] = Bs8[boff + 64 * j];
#pragma unroll
        for (int i = 0; i < 4; i++)
#pragma unroll
            for (int j = 0; j < 4; j++)
                acc[i][j] = __builtin_amdgcn_mfma_f32_16x16x32_bf16(af[i], bfv[j], acc[i][j], 0, 0, 0);
        __syncthreads();
    }
    int rbase = blockM + wm + (lane >> 4) * 4;
    int cbase = blockN + wn + (lane & 15);
    if (OUT_BF16) {
        u16* C = (u16*)Cp;
#pragma unroll
        for (int i = 0; i < 4; i++)
#pragma unroll
            for (int j = 0; j < 4; j++)
#pragma unroll
                for (int r = 0; r < 4; r++)
                    C[(size_t)(rbase + 16 * i + r) * ldC + cbase + 16 * j] = f2bf(acc[i][j][r]);
    } else {
        float* C = (float*)Cp;
#pragma unroll
        for (int i = 0; i < 4; i++)
#pragma unroll
            for (int j = 0; j < 4; j++)
#pragma unroll
                for (int r = 0; r < 4; r++)
                    C[(size_t)(rbase + 16 * i + r) * ldC + cbase + 16 * j] = acc[i][j][r];
    }
}

// ---------------- depthwise causal conv(4) + bias + silu; bf16 in/out ----------------
__global__ __launch_bounds__(256) void conv_kernel(const u16* __restrict__ xbcdt,
                                                   const float* __restrict__ conv_w,
                                                   const float* __restrict__ conv_b,
                                                   u16* __restrict__ convO) {
    int ch = blockIdx.x * 256 + threadIdx.x;  // 17*256 = 4352 exact
    int row = blockIdx.y;                     // 8192
    int l = row & (LTOT - 1);
    f4 w = *(const f4*)&conv_w[ch * 4];
    float acc = conv_b[ch];
#pragma unroll
    for (int k = 0; k < 4; ++k) {
        int ls = l - 3 + k;
        if (ls >= 0) acc += bf2f(xbcdt[(size_t)(row - 3 + k) * XBC_LD + ch]) * w[k];
    }
    convO[(size_t)row * CONV_DIM + ch] = f2bf(acc / (1.f + __expf(-acc)));
}

// ---------------- dt = softplus(raw + bias) -> dtp[row][h] f32 ----------------
__global__ __launch_bounds__(256) void dt_kernel(const u16* __restrict__ xbcdt,
                                                 const float* __restrict__ dt_bias,
                                                 float* __restrict__ dtp) {
    int idx = blockIdx.x * 256 + threadIdx.x;
    if (idx >= NB * LTOT * NHEADS) return;
    int row = idx >> 6, h = idx & 63;
    float x = bf2f(xbcdt[(size_t)row * XBC_LD + CONV_DIM + h]) + dt_bias[h];
    dtp[idx] = (x > 15.f) ? x : log1pf(__expf(x));
}

// ---------------- CB[l,s] = sum_n C[l,n]*B[s,n] per (b,c) -> CBb f32 ----------------
__global__ __launch_bounds__(256) void cb_kernel(const u16* __restrict__ convO,
                                                 float* __restrict__ CBb) {
    __shared__ u16 Bt[128 * 68];  // [n][s]
    __shared__ u16 Ct[128 * 68];  // [n][l]
    int bc = blockIdx.x;
    int c = bc & 63, b = bc >> 6;
    int rowbase = b * LTOT + c * CHUNK;
    int t = threadIdx.x;
#pragma unroll
    for (int i = 0; i < 32; i++) {
        int idx = i * 256 + t;
        int s = idx >> 7, n = idx & 127;
        Bt[n * 68 + s] = convO[(size_t)(rowbase + s) * CONV_DIM + D_SSM + n];
        Ct[n * 68 + s] = convO[(size_t)(rowbase + s) * CONV_DIM + D_SSM + D_STATE + n];
    }
    __syncthreads();
    int sq = t & 15, lq = t >> 4;
    f4 acc[4] = {};
#pragma unroll 4
    for (int n = 0; n < 128; n++) {
        ushort4 bv = *(const ushort4*)&Bt[n * 68 + sq * 4];
        ushort4 cv = *(const ushort4*)&Ct[n * 68 + lq * 4];
        f4 bf;
        bf[0] = bf2f(bv.x); bf[1] = bf2f(bv.y); bf[2] = bf2f(bv.z); bf[3] = bf2f(bv.w);
        float c0 = bf2f(cv.x), c1 = bf2f(cv.y), c2 = bf2f(cv.z), c3 = bf2f(cv.w);
        acc[0] += c0 * bf; acc[1] += c1 * bf; acc[2] += c2 * bf; acc[3] += c3 * bf;
    }
    float* outb = CBb + (size_t)bc * 4096;
#pragma unroll
    for (int j = 0; j < 4; j++) *(f4*)&outb[(lq * 4 + j) * 64 + sq * 4] = acc[j];
}

// ---------------- fused SSM, MFMA version (deep-prefetch pipeline) ----------
// grid 512 = (b 2) x (h 64) x (pg 4); block 256 (4 waves); sequential over 64 chunks.
// Pipeline: operands (C rows, CB rows) for chunk c+1 are loaded during iteration c
// and consumed a full iteration later; LDS tiles (x,B,dt-scan,Sd) double-buffered
// one chunk ahead; y output deferred one chunk (stored at the top of the next
// iteration so the pre-barrier vmcnt(0) drain never waits on a fresh store).
// In steady state no s_waitcnt in the loop should block.
__global__ __launch_bounds__(256, 2) void ssm_mfma(const u16* __restrict__ convO,
                                                   const float* __restrict__ dtp,
                                                   const float* __restrict__ CBb,
                                                   const float* __restrict__ A_log,
                                                   const float* __restrict__ Dvec,
                                                   u16* __restrict__ ybf) {
    __shared__ __align__(16) u16 xT[2][16 * 72];    // [p'][l]
    __shared__ __align__(16) u16 BT[2][128 * 72];   // [n][l]
    __shared__ __align__(16) u16 Sd[2][16 * 136];   // [p'][n]
    __shared__ __align__(16) float scal[2][256];    // dts|acs|wls|els, 64 each

    int t = threadIdx.x;
    int w = t >> 6, lane = t & 63;
    int z = blockIdx.x;
    int pg = z & 3, h = (z >> 2) & 63, b = z >> 8;
    int pbase = h * 64 + pg * 16;
    float Ah = -__expf(A_log[h]);
    float Dh = Dvec[h];

    int fm = lane & 15;        // within-tile row/col index
    int fq = lane >> 4;        // quad 0..3
    int fk = fq * 8;           // k-base within a 32-wide k-step
    int sl = t & 63;           // staging: row l
    int sq = t >> 6;           // staging: quarter

    f32x4 sacc[2] = {};        // state acc: element (p' = fq*4+r, n = 32w+16nt+fm)

    const float* CBbase = CBb + (size_t)(b * 64) * 4096;
    int yl = 16 * w + fm;      // A-operand row l for Y mfmas

    // ---------- prologue: stage chunk 0 into buffers[0]; load operands for chunk 0 ----
    bf16x8 afr[4];             // C rows for current chunk (loaded one iter ahead)
    f4 cbr[2][2];              // CB rows for current chunk
    {
        int rowbase = b * LTOT;
        const u16* rowp = convO + (size_t)rowbase * CONV_DIM;
        // operands for chunk 0
        const u16* Cg = rowp + (size_t)yl * CONV_DIM + D_SSM + D_STATE;
#pragma unroll
        for (int kk = 0; kk < 4; ++kk) afr[kk] = *(const bf16x8*)(Cg + kk * 32 + fk);
        const float* CBrow = CBbase + yl * 64;
#pragma unroll
        for (int kk = 0; kk < 2; ++kk) {
            cbr[kk][0] = *(const f4*)&CBrow[kk * 32 + fk];
            cbr[kk][1] = *(const f4*)&CBrow[kk * 32 + fk + 4];
        }
        // LDS tiles for chunk 0
        if (t < 64) {
            float dtv = dtp[(size_t)(rowbase + t) * 64 + h];
            float v = dtv * Ah;
#pragma unroll
            for (int off = 1; off < 64; off <<= 1) {
                float pv = __shfl_up(v, off, 64);
                if (t >= off) v += pv;
            }
            float alast = __shfl(v, 63, 64);
            scal[0][t] = dtv;
            scal[0][64 + t] = v;
            scal[0][128 + t] = dtv * __expf(alast - v);
            scal[0][192 + t] = __expf(v);
        }
        ushort4 xv = *(const ushort4*)(rowp + (size_t)sl * CONV_DIM + pbase + sq * 4);
        xT[0][(sq * 4 + 0) * 72 + sl] = xv.x;
        xT[0][(sq * 4 + 1) * 72 + sl] = xv.y;
        xT[0][(sq * 4 + 2) * 72 + sl] = xv.z;
        xT[0][(sq * 4 + 3) * 72 + sl] = xv.w;
        {
            const uint4* bp = (const uint4*)(rowp + (size_t)sl * CONV_DIM + D_SSM + sq * 32);
            uint4 bvp[4];
#pragma unroll
            for (int q = 0; q < 4; ++q) bvp[q] = bp[q];
            const u16* bs = (const u16*)bvp;
#pragma unroll
            for (int i = 0; i < 32; ++i) BT[0][(sq * 32 + i) * 72 + sl] = bs[i];
        }
#pragma unroll
        for (int nt = 0; nt < 2; ++nt)
#pragma unroll
            for (int r = 0; r < 4; ++r)
                Sd[0][(fq * 4 + r) * 136 + 32 * w + 16 * nt + fm] = 0;
        __syncthreads();
    }

    f4 ydef = {0.f, 0.f, 0.f, 0.f};   // deferred y values for chunk c-1
    int cur = 0;
    for (int c = 0; c < 64; ++c, cur ^= 1) {
        int rowbase = b * LTOT + c * CHUNK;
        const u16* rowp = convO + (size_t)rowbase * CONV_DIM;

        // ---- deferred y store for chunk c-1 (stores retire during this iteration) ----
        if (c > 0) {
            int rbp = rowbase - CHUNK;
#pragma unroll
            for (int r = 0; r < 4; ++r) {
                int l = 16 * w + fq * 4 + r;
                ybf[(size_t)(rbp + l) * D_SSM + pbase + fm] = f2bf(ydef[r]);
            }
        }

        // ---- next-chunk operand prefetch (C, CB rows for chunk c+1 -> regs) ----
        bf16x8 afr_n[4] = {};
        f4 cbr_n[2][2] = {};
        uint4 bv[4] = {};
        ushort4 xv = {0, 0, 0, 0};
        float dtv = 0.f;
        if (c < 63) {
            const u16* rowp1 = rowp + (size_t)CHUNK * CONV_DIM;
            const u16* Cg = rowp1 + (size_t)yl * CONV_DIM + D_SSM + D_STATE;
#pragma unroll
            for (int kk = 0; kk < 4; ++kk) afr_n[kk] = *(const bf16x8*)(Cg + kk * 32 + fk);
            const float* CBrow = CBbase + (size_t)(c + 1) * 4096 + yl * 64;
#pragma unroll
            for (int kk = 0; kk < 2; ++kk) {
                cbr_n[kk][0] = *(const f4*)&CBrow[kk * 32 + fk];
                cbr_n[kk][1] = *(const f4*)&CBrow[kk * 32 + fk + 4];
            }
            // LDS staging loads for chunk c+1 (consumed in write phase)
            const uint4* bp = (const uint4*)(rowp1 + (size_t)sl * CONV_DIM + D_SSM + sq * 32);
#pragma unroll
            for (int q = 0; q < 4; ++q) bv[q] = bp[q];
            xv = *(const ushort4*)(rowp1 + (size_t)sl * CONV_DIM + pbase + sq * 4);
            if (t < 64) dtv = dtp[(size_t)(rowbase + CHUNK + t) * 64 + h];
        }

        const float* sc = scal[cur];
        const u16* xTc = xT[cur];
        const u16* BTc = BT[cur];
        const u16* Sdc = Sd[cur];

        // ---- Y_off = C . S^T (operands afr loaded one full iteration ago) ----
        f32x4 yacc = {0.f, 0.f, 0.f, 0.f};
#pragma unroll
        for (int kk = 0; kk < 4; ++kk) {
            bf16x8 bfr = *(const bf16x8*)&Sdc[fm * 136 + kk * 32 + fk];
            yacc = __builtin_amdgcn_mfma_f32_16x16x32_bf16(afr[kk], bfr, yacc, 0, 0, 0);
        }
#pragma unroll
        for (int r = 0; r < 4; ++r) yacc[r] *= sc[192 + 16 * w + fq * 4 + r];

        // ---- Y_diag = G . x ----
        {
            float acl = sc[64 + yl];
#pragma unroll
            for (int kk = 0; kk < 2; ++kk) {
                int s0 = kk * 32 + fk;
                f4 cb0 = cbr[kk][0];
                f4 cb1 = cbr[kk][1];
                f4 ac0 = *(const f4*)&sc[64 + s0];
                f4 ac1 = *(const f4*)&sc[64 + s0 + 4];
                f4 dt0 = *(const f4*)&sc[s0];
                f4 dt1 = *(const f4*)&sc[s0 + 4];
                union { u16 us[8]; bf16x8 v; } gu;
#pragma unroll
                for (int j = 0; j < 4; ++j) {
                    int s = s0 + j;
                    float gv = (s <= yl) ? cb0[j] * __expf(acl - ac0[j]) * dt0[j] : 0.f;
                    gu.us[j] = f2bf(gv);
                }
#pragma unroll
                for (int j = 0; j < 4; ++j) {
                    int s = s0 + 4 + j;
                    float gv = (s <= yl) ? cb1[j] * __expf(acl - ac1[j]) * dt1[j] : 0.f;
                    gu.us[4 + j] = f2bf(gv);
                }
                bf16x8 xfr = *(const bf16x8*)&xTc[fm * 72 + s0];
                yacc = __builtin_amdgcn_mfma_f32_16x16x32_bf16(gu.v, xfr, yacc, 0, 0, 0);
            }
        }

        // ---- epilogue: += D*x, keep in regs (stored at top of next iteration) ----
#pragma unroll
        for (int r = 0; r < 4; ++r) {
            int l = 16 * w + fq * 4 + r;
            float xvv = bf2f(xTc[fm * 72 + l]);
            ydef[r] = yacc[r] + Dh * xvv;
        }

        // ---- state update: S = cd*S + (w.x)^T . B ----
        float cd = sc[192 + 63];
        sacc[0] *= cd;
        sacc[1] *= cd;
#pragma unroll
        for (int kk = 0; kk < 2; ++kk) {
            int l0 = kk * 32 + fk;
            ushort4 x0 = *(const ushort4*)&xTc[fm * 72 + l0];
            ushort4 x1 = *(const ushort4*)&xTc[fm * 72 + l0 + 4];
            f4 w0 = *(const f4*)&sc[128 + l0];
            f4 w1 = *(const f4*)&sc[128 + l0 + 4];
            union { u16 us[8]; bf16x8 v; } au;
            au.us[0] = f2bf(bf2f(x0.x) * w0[0]);
            au.us[1] = f2bf(bf2f(x0.y) * w0[1]);
            au.us[2] = f2bf(bf2f(x0.z) * w0[2]);
            au.us[3] = f2bf(bf2f(x0.w) * w0[3]);
            au.us[4] = f2bf(bf2f(x1.x) * w1[0]);
            au.us[5] = f2bf(bf2f(x1.y) * w1[1]);
            au.us[6] = f2bf(bf2f(x1.z) * w1[2]);
            au.us[7] = f2bf(bf2f(x1.w) * w1[3]);
#pragma unroll
            for (int nt = 0; nt < 2; ++nt) {
                bf16x8 bfr = *(const bf16x8*)&BTc[(32 * w + 16 * nt + fm) * 72 + l0];
                sacc[nt] = __builtin_amdgcn_mfma_f32_16x16x32_bf16(au.v, bfr, sacc[nt], 0, 0, 0);
            }
        }

        // ---- write phase: stage chunk c+1 into buffers[nxt] ----
        if (c < 63) {
            int nxt = cur ^ 1;
            if (t < 64) {
                float v = dtv * Ah;
#pragma unroll
                for (int off = 1; off < 64; off <<= 1) {
                    float pv = __shfl_up(v, off, 64);
                    if (t >= off) v += pv;
                }
                float alast = __shfl(v, 63, 64);
                scal[nxt][t] = dtv;
                scal[nxt][64 + t] = v;
                scal[nxt][128 + t] = dtv * __expf(alast - v);
                scal[nxt][192 + t] = __expf(v);
            }
            xT[nxt][(sq * 4 + 0) * 72 + sl] = xv.x;
            xT[nxt][(sq * 4 + 1) * 72 + sl] = xv.y;
            xT[nxt][(sq * 4 + 2) * 72 + sl] = xv.z;
            xT[nxt][(sq * 4 + 3) * 72 + sl] = xv.w;
            {
                const u16* bs = (const u16*)bv;
#pragma unroll
                for (int i = 0; i < 32; ++i) BT[nxt][(sq * 32 + i) * 72 + sl] = bs[i];
            }
#pragma unroll
            for (int nt = 0; nt < 2; ++nt)
#pragma unroll
                for (int r = 0; r < 4; ++r)
                    Sd[nxt][(fq * 4 + r) * 136 + 32 * w + 16 * nt + fm] = f2bf(sacc[nt][r]);
        }
        __syncthreads();

        // rotate prefetched operands into the "current" slots (register moves)
#pragma unroll
        for (int kk = 0; kk < 4; ++kk) afr[kk] = afr_n[kk];
#pragma unroll
        for (int kk = 0; kk < 2; ++kk) {
            cbr[kk][0] = cbr_n[kk][0];
            cbr[kk][1] = cbr_n[kk][1];
        }
    }

    // final deferred y store (chunk 63)
    {
        int rbp = b * LTOT + 63 * CHUNK;
#pragma unroll
        for (int r = 0; r < 4; ++r) {
            int l = 16 * w + fq * 4 + r;
            ybf[(size_t)(rbp + l) * D_SSM + pbase + fm] = f2bf(ydef[r]);
        }
    }
}

// ---------------- gate (silu(z)) + RMSNorm, in-place on y_bf ----------------
__global__ __launch_bounds__(256) void gate_norm(const u16* __restrict__ zbf,
                                                 const float* __restrict__ normw,
                                                 u16* __restrict__ ybf) {
    int row = blockIdx.x, t = threadIdx.x;
    const uint2* y2 = (const uint2*)(ybf + (size_t)row * D_SSM);
    const uint2* z2 = (const uint2*)(zbf + (size_t)row * D_SSM);
    f4 yg[4];
    float ss = 0.f;
#pragma unroll
    for (int i = 0; i < 4; ++i) {
        int idx = i * 256 + t;
        uint2 yv = y2[idx], zv = z2[idx];
        float ya[4] = {bf2f(yv.x & 0xffffu), bf2f(yv.x >> 16), bf2f(yv.y & 0xffffu), bf2f(yv.y >> 16)};
        float za[4] = {bf2f(zv.x & 0xffffu), bf2f(zv.x >> 16), bf2f(zv.y & 0xffffu), bf2f(zv.y >> 16)};
        f4 g;
#pragma unroll
        for (int k = 0; k < 4; ++k) {
            float sz = za[k] / (1.f + __expf(-za[k]));
            g[k] = ya[k] * sz;
            ss += g[k] * g[k];
        }
        yg[i] = g;
    }
#pragma unroll
    for (int off = 32; off; off >>= 1) ss += __shfl_down(ss, off, 64);
    __shared__ float red[4];
    if ((t & 63) == 0) red[t >> 6] = ss;
    __syncthreads();
    float tot = red[0] + red[1] + red[2] + red[3];
    float scale = rsqrtf(tot / (float)D_SSM + 1e-5f);
    const f4* nw4 = (const f4*)normw;
    uint2* out = (uint2*)(ybf + (size_t)row * D_SSM);
#pragma unroll
    for (int i = 0; i < 4; ++i) {
        int idx = i * 256 + t;
        f4 v = yg[i] * scale * nw4[idx];
        uint2 pk;
        pk.x = pack2(v[0], v[1]);
        pk.y = pack2(v[2], v[3]);
        out[idx] = pk;
    }
}

// ---------------- launch ----------------
extern "C" void kernel_launch(void* const* d_in, const int* in_sizes, int n_in,
                              void* d_out, int out_size, void* d_ws, size_t ws_size,
                              hipStream_t stream) {
    const float* u = (const float*)d_in[0];
    const float* W_in = (const float*)d_in[1];
    const float* conv_w = (const float*)d_in[2];
    const float* conv_b = (const float*)d_in[3];
    const float* dt_bias = (const float*)d_in[4];
    const float* A_log = (const float*)d_in[5];
    const float* Dv = (const float*)d_in[6];
    const float* normw = (const float*)d_in[7];
    const float* W_out = (const float*)d_in[8];
    float* out = (float*)d_out;
    char* ws = (char*)d_ws;

    // workspace layout (total 216,006,656 B ~= 206 MiB) — same proven layout as round 2
    u16* z_bf = (u16*)(ws + 0ULL);              //  8192x4096 bf16 = 67,108,864
    u16* xbcdt = (u16*)(ws + 67108864ULL);      //  8192x4480 bf16 = 73,400,320
    u16* y_bf = xbcdt;                          //  overlay: 8192x4096 bf16 (xbcdt dead after conv+dt)
    u16* convO = (u16*)(ws + 140509184ULL);     //  8192x4352 bf16 = 71,303,168
    u16* u_bf = convO;                          //  overlay: 33,554,432 (dead before conv writes)
    u16* win_bf = (u16*)(ws + 174063616ULL);    //  overlay: 35,127,296 (dead before conv writes)
    u16* wout_bf = convO;                       //  overlay: 16,777,216 (after ssm)
    float* dtp = (float*)(ws + 211812352ULL);   //  8192x64 f32 = 2,097,152
    float* CBb = (float*)(ws + 213909504ULL);   //  128x64x64 f32 = 2,097,152

    tobf16_kernel<<<16384, 256, 0, stream>>>(u, u_bf, 4194304);
    winpad_kernel<<<17152, 256, 0, stream>>>(W_in, win_bf);
    gemm_bt<1><<<dim3(32, 64), 256, 0, stream>>>(u_bf, win_bf, z_bf, 2048, 4096);
    gemm_bt<1><<<dim3(35, 64), 256, 0, stream>>>(u_bf, win_bf + (size_t)4096 * 2048, xbcdt, 2048, XBC_LD);
    conv_kernel<<<dim3(17, 8192), 256, 0, stream>>>(xbcdt, conv_w, conv_b, convO);
    dt_kernel<<<2048, 256, 0, stream>>>(xbcdt, dt_bias, dtp);
    cb_kernel<<<128, 256, 0, stream>>>(convO, CBb);
    ssm_mfma<<<512, 256, 0, stream>>>(convO, dtp, CBb, A_log, Dv, y_bf);
    tobf16_kernel<<<8192, 256, 0, stream>>>(W_out, wout_bf, 2097152);
    gate_norm<<<8192, 256, 0, stream>>>(z_bf, normw, y_bf);
    gemm_bt<0><<<dim3(16, 64), 256, 0, stream>>>(y_bf, wout_bf, out, 4096, 2048);
}